// Round 1
// baseline (22975.569 us; speedup 1.0000x reference)
//
#include <hip/hip_runtime.h>
#include <math.h>

constexpr int Bsz = 256, Tsz = 1024, Isz = 64, Hsz = 256, Osz = 8;
constexpr int NB  = 4;              // batch rows per workgroup
constexpr int K   = Hsz + Isz;      // 320

__global__ __launch_bounds__(256) void lstm_fused(
    const float* __restrict__ x,
    const float* __restrict__ W_f, const float* __restrict__ b_f,
    const float* __restrict__ W_i, const float* __restrict__ b_i,
    const float* __restrict__ W_c, const float* __restrict__ b_c,
    const float* __restrict__ W_o, const float* __restrict__ b_o,
    const float* __restrict__ W_ho, const float* __restrict__ b_ho,
    float* __restrict__ out)
{
    // comb[b][0:256] = h,  comb[b][256:320] = x_t   (matches reference concat [h, x_t])
    __shared__ float comb[NB][K];
    const int j  = threadIdx.x;       // h-column owned by this thread
    const int b0 = blockIdx.x * NB;

    // h = 0; stage x[t=0]
    #pragma unroll
    for (int b = 0; b < NB; ++b) comb[b][j] = 0.0f;
    {
        const int b = j >> 6, i = j & 63;
        comb[b][Hsz + i] = x[((size_t)(b0 + b) * Tsz) * Isz + i];
    }
    __syncthreads();

    float c[NB];
    #pragma unroll
    for (int b = 0; b < NB; ++b) c[b] = 0.0f;

    const float bf = b_f[j], bi = b_i[j], bc = b_c[j], bo = b_o[j];

    for (int t = 0; t < Tsz; ++t) {
        float gf[NB], gi[NB], gc[NB], go[NB];
        #pragma unroll
        for (int b = 0; b < NB; ++b) { gf[b] = bf; gi[b] = bi; gc[b] = bc; go[b] = bo; }

        // g[b, {f,i,c,o} col j] = sum_k comb[b][k] * W_*[k][j]
        // weight loads: lane j -> W[k*256 + j]: fully coalesced, L2-resident (1.25MB)
        // comb reads: all lanes same address -> LDS broadcast
        #pragma unroll 4
        for (int k = 0; k < K; ++k) {
            const float wf = W_f[k * Hsz + j];
            const float wi = W_i[k * Hsz + j];
            const float wc = W_c[k * Hsz + j];
            const float wo = W_o[k * Hsz + j];
            #pragma unroll
            for (int b = 0; b < NB; ++b) {
                const float v = comb[b][k];
                gf[b] = fmaf(v, wf, gf[b]);
                gi[b] = fmaf(v, wi, gi[b]);
                gc[b] = fmaf(v, wc, gc[b]);
                go[b] = fmaf(v, wo, go[b]);
            }
        }
        __syncthreads();   // everyone done reading comb for step t

        #pragma unroll
        for (int b = 0; b < NB; ++b) {
            const float f  = 1.0f / (1.0f + expf(-gf[b]));
            const float ig = 1.0f / (1.0f + expf(-gi[b]));
            const float ch = tanhf(gc[b]);
            const float og = 1.0f / (1.0f + expf(-go[b]));
            c[b] = f * c[b] + ig * ch;
            comb[b][j] = og * tanhf(c[b]);      // h_new
        }
        if (t + 1 < Tsz) {
            const int b = j >> 6, i2 = j & 63;
            comb[b][Hsz + i2] = x[((size_t)(b0 + b) * Tsz + (t + 1)) * Isz + i2];
        }
        __syncthreads();
    }

    // out[b,:] = h_T @ W_ho + b_ho   (256x8), 32 threads do the 32 dots
    if (j < NB * Osz) {
        const int b = j >> 3, o = j & 7;
        float acc = b_ho[o];
        #pragma unroll 8
        for (int k = 0; k < Hsz; ++k)
            acc = fmaf(comb[b][k], W_ho[k * Osz + o], acc);
        out[(size_t)(b0 + b) * Osz + o] = acc;
    }
}

extern "C" void kernel_launch(void* const* d_in, const int* in_sizes, int n_in,
                              void* d_out, int out_size, void* d_ws, size_t ws_size,
                              hipStream_t stream) {
    const float* x    = (const float*)d_in[0];
    const float* W_f  = (const float*)d_in[1];
    const float* b_f  = (const float*)d_in[2];
    const float* W_i  = (const float*)d_in[3];
    const float* b_i  = (const float*)d_in[4];
    const float* W_c  = (const float*)d_in[5];
    const float* b_c  = (const float*)d_in[6];
    const float* W_o  = (const float*)d_in[7];
    const float* b_o  = (const float*)d_in[8];
    const float* W_ho = (const float*)d_in[9];
    const float* b_ho = (const float*)d_in[10];
    float* out = (float*)d_out;

    lstm_fused<<<Bsz / NB, 256, 0, stream>>>(
        x, W_f, b_f, W_i, b_i, W_c, b_c, W_o, b_o, W_ho, b_ho, out);
}